// Round 1
// baseline (470.768 us; speedup 1.0000x reference)
//
#include <hip/hip_runtime.h>

#define BATCH 2048
#define NB 254

// 4-byte-aligned float4 for unaligned gathers (hardware supports align-4 dwordx4)
typedef float f4u __attribute__((ext_vector_type(4), aligned(4)));

__device__ __forceinline__ float selw(int pd, float w0, float w1, float w2, float w3) {
    return (pd == 0) ? w0 : (pd == 1) ? w1 : (pd == 2) ? w2 : (pd == 3) ? w3 : 0.f;
}

// Per (b,i): silu(x)*wb, 4 spline tap weights *ws (shifted into clamped window), window start j.
__global__ __launch_bounds__(256) void basis_kernel(
    const float* __restrict__ act, int IN,
    const float* __restrict__ wbp, const float* __restrict__ wsp,
    float* __restrict__ sbuf, float4* __restrict__ vbuf, int* __restrict__ jbuf)
{
    int idx = blockIdx.x * 256 + threadIdx.x;
    int total = BATCH * IN;
    if (idx >= total) return;
    int i = idx / BATCH;
    int b = idx - i * BATCH;

    float x = act[(size_t)b * IN + i];
    float wb = wbp[0], wsc = wsp[0];

    float sil = x / (1.f + __expf(-x));

    const float LO = -0.05f;
    const float INVH = 228.18181818181818f;  // 251/1.1
    float uf = (x - LO) * INVH;
    float fm = floorf(uf);
    float t = uf - fm;
    int M = (int)fm + 3;     // grid interval index: x in [GRID[M], GRID[M+1])

    bool valid = (M >= 0) && (M <= 256);
    float wsv = valid ? wsc : 0.f;

    float omt = 1.f - t;
    float t2 = t * t, t3 = t2 * t;
    const float S = 1.f / 6.f;
    float w0 = omt * omt * omt * S * wsv;
    float w1 = (3.f * t3 - 6.f * t2 + 4.f) * S * wsv;
    float w2 = (-3.f * t3 + 3.f * t2 + 3.f * t + 1.f) * S * wsv;
    float w3 = t3 * S * wsv;

    int js = M - 3;
    js = js < 0 ? 0 : js;
    js = js > (NB - 4) ? (NB - 4) : js;
    if (!valid) js = 0;
    int d = js - (M - 3);    // shift of taps inside the clamped window, in [-3,3]

    float vp0 = selw(0 + d, w0, w1, w2, w3);
    float vp1 = selw(1 + d, w0, w1, w2, w3);
    float vp2 = selw(2 + d, w0, w1, w2, w3);
    float vp3 = selw(3 + d, w0, w1, w2, w3);
    // drop taps whose true basis index is out of [0, NB): handled by shift construction,
    // since window [js, js+3] stays inside [0, NB) and only overlapping taps map in.

    sbuf[idx] = sil * wb;
    vbuf[idx] = make_float4(vp0, vp1, vp2, vp3);
    jbuf[idx] = js;
}

// out[b, o0..o0+OT) = sum_i ( s[b,i]*bw[o,i] + dot(v4[b,i], sw[o,i,j..j+3]) ) (+resid)
template<int IN, int OT, bool RES>
__global__ __launch_bounds__(256) void accum_kernel(
    const float* __restrict__ sbuf, const float4* __restrict__ vbuf,
    const int* __restrict__ jbuf, const float* __restrict__ bw,
    const float* __restrict__ sw, const float* __restrict__ resid,
    float* __restrict__ out, int OUTF)
{
    int tid = threadIdx.x;
    int b = blockIdx.y * 256 + tid;
    int o0 = blockIdx.x * OT;

    float acc[OT];
#pragma unroll
    for (int k = 0; k < OT; k++) acc[k] = 0.f;

    const size_t ostride = (size_t)IN * NB;

    for (int i = 0; i < IN; i++) {
        float s = sbuf[i * BATCH + b];
        float4 v = vbuf[i * BATCH + b];
        int j = jbuf[i * BATCH + b];
        const float* p = sw + (size_t)(o0 * IN + i) * NB + j;
        const float* bq = bw + o0 * IN + i;
#pragma unroll
        for (int oo = 0; oo < OT; oo++) {
            f4u w = *(const f4u*)(p + (size_t)oo * ostride);
            float bwv = bq[oo * IN];
            acc[oo] += s * bwv + v.x * w[0] + v.y * w[1] + v.z * w[2] + v.w * w[3];
        }
    }

    float* op = out + (size_t)b * OUTF + o0;
#pragma unroll
    for (int oo = 0; oo < OT; oo++) {
        float r = RES ? resid[(size_t)b * OUTF + o0 + oo] : 0.f;
        op[oo] = acc[oo] + r;
    }
}

// Final layer: out=1. 16 threads per batch row, shuffle-reduce.
__global__ __launch_bounds__(256) void out_kernel(
    const float* __restrict__ sbuf, const float4* __restrict__ vbuf,
    const int* __restrict__ jbuf, const float* __restrict__ bw,
    const float* __restrict__ sw, float* __restrict__ out)
{
    int tid = threadIdx.x;
    int bl = tid >> 4;
    int ig = tid & 15;
    int b = blockIdx.x * 16 + bl;

    float acc = 0.f;
    for (int ii = ig; ii < 256; ii += 16) {
        float s = sbuf[ii * BATCH + b];
        float4 v = vbuf[ii * BATCH + b];
        int j = jbuf[ii * BATCH + b];
        const float* p = sw + (size_t)ii * NB + j;
        acc += s * bw[ii] + v.x * p[0] + v.y * p[1] + v.z * p[2] + v.w * p[3];
    }
#pragma unroll
    for (int dlt = 8; dlt >= 1; dlt >>= 1) acc += __shfl_down(acc, dlt, 16);
    if (ig == 0) out[b] = acc;
}

extern "C" void kernel_launch(void* const* d_in, const int* in_sizes, int n_in,
                              void* d_out, int out_size, void* d_ws, size_t ws_size,
                              hipStream_t stream)
{
    const float* x   = (const float*)d_in[0];
    const float* bw0 = (const float*)d_in[1];
    const float* sw0 = (const float*)d_in[2];
    const float* wb0 = (const float*)d_in[3];
    const float* ws0 = (const float*)d_in[4];
    const float* bw1 = (const float*)d_in[5];
    const float* sw1 = (const float*)d_in[6];
    const float* wb1 = (const float*)d_in[7];
    const float* ws1 = (const float*)d_in[8];
    const float* bw2 = (const float*)d_in[9];
    const float* sw2 = (const float*)d_in[10];
    const float* wb2 = (const float*)d_in[11];
    const float* ws2 = (const float*)d_in[12];
    const float* bw3 = (const float*)d_in[13];
    const float* sw3 = (const float*)d_in[14];
    const float* wb3 = (const float*)d_in[15];
    const float* ws3 = (const float*)d_in[16];

    char* ws = (char*)d_ws;
    float4* vbuf = (float4*)(ws);                        // 8 MB
    float*  sbuf = (float*)(ws + 8  * 1024 * 1024);      // 2 MB
    int*    jbuf = (int*)  (ws + 10 * 1024 * 1024);      // 2 MB
    float*  hA   = (float*)(ws + 12 * 1024 * 1024);      // 2 MB
    float*  hB   = (float*)(ws + 14 * 1024 * 1024);      // 2 MB

    float* out = (float*)d_out;

    // Layer 0: 64 -> 256, no residual
    basis_kernel<<<(BATCH * 64 + 255) / 256, 256, 0, stream>>>(x, 64, wb0, ws0, sbuf, vbuf, jbuf);
    accum_kernel<64, 8, false><<<dim3(32, 8), 256, 0, stream>>>(sbuf, vbuf, jbuf, bw0, sw0, nullptr, hA, 256);

    // Layer 1: 256 -> 256, residual
    basis_kernel<<<(BATCH * 256 + 255) / 256, 256, 0, stream>>>(hA, 256, wb1, ws1, sbuf, vbuf, jbuf);
    accum_kernel<256, 8, true><<<dim3(32, 8), 256, 0, stream>>>(sbuf, vbuf, jbuf, bw1, sw1, hA, hB, 256);

    // Layer 2: 256 -> 256, residual
    basis_kernel<<<(BATCH * 256 + 255) / 256, 256, 0, stream>>>(hB, 256, wb2, ws2, sbuf, vbuf, jbuf);
    accum_kernel<256, 8, true><<<dim3(32, 8), 256, 0, stream>>>(sbuf, vbuf, jbuf, bw2, sw2, hB, hA, 256);

    // Layer 3: 256 -> 1, no residual
    basis_kernel<<<(BATCH * 256 + 255) / 256, 256, 0, stream>>>(hA, 256, wb3, ws3, sbuf, vbuf, jbuf);
    out_kernel<<<BATCH / 16, 256, 0, stream>>>(sbuf, vbuf, jbuf, bw3, sw3, out);
}

// Round 2
// 299.904 us; speedup vs baseline: 1.5697x; 1.5697x over previous
//
#include <hip/hip_runtime.h>

#define BATCH 2048
#define NB 254

// 4-byte-aligned float4 for unaligned gathers (hardware supports align-4 dwordx4)
typedef float f4u __attribute__((ext_vector_type(4), aligned(4)));

__device__ __forceinline__ float selw(int pd, float w0, float w1, float w2, float w3) {
    return (pd == 0) ? w0 : (pd == 1) ? w1 : (pd == 2) ? w2 : (pd == 3) ? w3 : 0.f;
}

// Per (b,i): silu(x)*wb, 4 spline tap weights *ws (shifted into clamped window), window start j.
__global__ __launch_bounds__(256) void basis_kernel(
    const float* __restrict__ act, int IN,
    const float* __restrict__ wbp, const float* __restrict__ wsp,
    float* __restrict__ sbuf, float4* __restrict__ vbuf, int* __restrict__ jbuf)
{
    int idx = blockIdx.x * 256 + threadIdx.x;
    int total = BATCH * IN;
    if (idx >= total) return;
    int i = idx / BATCH;
    int b = idx - i * BATCH;

    float x = act[(size_t)b * IN + i];
    float wb = wbp[0], wsc = wsp[0];

    float sil = x / (1.f + __expf(-x));

    const float LO = -0.05f;
    const float INVH = 228.18181818181818f;  // 251/1.1
    float uf = (x - LO) * INVH;
    float fm = floorf(uf);
    float t = uf - fm;
    int M = (int)fm + 3;     // grid interval index: x in [GRID[M], GRID[M+1])

    bool valid = (M >= 0) && (M <= 256);
    float wsv = valid ? wsc : 0.f;

    float omt = 1.f - t;
    float t2 = t * t, t3 = t2 * t;
    const float S = 1.f / 6.f;
    float w0 = omt * omt * omt * S * wsv;
    float w1 = (3.f * t3 - 6.f * t2 + 4.f) * S * wsv;
    float w2 = (-3.f * t3 + 3.f * t2 + 3.f * t + 1.f) * S * wsv;
    float w3 = t3 * S * wsv;

    int js = M - 3;
    js = js < 0 ? 0 : js;
    js = js > (NB - 4) ? (NB - 4) : js;
    if (!valid) js = 0;
    int d = js - (M - 3);    // shift of taps inside the clamped window, in [-3,3]

    float vp0 = selw(0 + d, w0, w1, w2, w3);
    float vp1 = selw(1 + d, w0, w1, w2, w3);
    float vp2 = selw(2 + d, w0, w1, w2, w3);
    float vp3 = selw(3 + d, w0, w1, w2, w3);

    sbuf[idx] = sil * wb;
    vbuf[idx] = make_float4(vp0, vp1, vp2, vp3);
    jbuf[idx] = js;
}

// out[b, o0..o0+OT) = sum_i ( s[b,i]*bw[o,i] + dot(v4[b,i], sw[o,i,j..j+3]) ) (+resid)
// Block: BT b-lanes (x) * IG i-groups (y). Each group reduces IN/IG i's, LDS tree at end.
template<int IN, int OT, bool RES, int IG, int BT>
__global__ __launch_bounds__(BT * IG) void accum_kernel(
    const float* __restrict__ sbuf, const float4* __restrict__ vbuf,
    const int* __restrict__ jbuf, const float* __restrict__ bw,
    const float* __restrict__ sw, const float* __restrict__ resid,
    float* __restrict__ out, int OUTF)
{
    int bx = threadIdx.x;              // b lane within tile
    int g  = threadIdx.y;              // i-group
    int b  = blockIdx.y * BT + bx;
    int o0 = blockIdx.x * OT;

    float acc[OT];
#pragma unroll
    for (int k = 0; k < OT; k++) acc[k] = 0.f;

    const size_t ostride = (size_t)IN * NB;
    const int CH = IN / IG;
    const int i0 = g * CH;

    for (int ii = 0; ii < CH; ii++) {
        int i = i0 + ii;
        float s = sbuf[i * BATCH + b];
        float4 v = vbuf[i * BATCH + b];
        int j = jbuf[i * BATCH + b];
        const float* p = sw + (size_t)(o0 * IN + i) * NB + j;
        const float* bq = bw + o0 * IN + i;
#pragma unroll
        for (int oo = 0; oo < OT; oo++) {
            f4u w = *(const f4u*)(p + (size_t)oo * ostride);
            float bwv = bq[oo * IN];
            acc[oo] += s * bwv + v.x * w[0] + v.y * w[1] + v.z * w[2] + v.w * w[3];
        }
    }

    // LDS reduce across i-groups. Layout [oo][g-1][bx]: lane-stride 1, conflict-free.
    __shared__ float lds[OT * (IG - 1) * BT];
    if (g > 0) {
#pragma unroll
        for (int oo = 0; oo < OT; oo++)
            lds[(oo * (IG - 1) + (g - 1)) * BT + bx] = acc[oo];
    }
    __syncthreads();
    if (g == 0) {
#pragma unroll
        for (int oo = 0; oo < OT; oo++) {
            float a = acc[oo];
            for (int gg = 1; gg < IG; gg++)
                a += lds[(oo * (IG - 1) + (gg - 1)) * BT + bx];
            float r = RES ? resid[(size_t)b * OUTF + o0 + oo] : 0.f;
            out[(size_t)b * OUTF + o0 + oo] = a + r;
        }
    }
}

// Final layer: out=1. 64 lanes per batch row, shuffle-reduce.
__global__ __launch_bounds__(256) void out_kernel(
    const float* __restrict__ sbuf, const float4* __restrict__ vbuf,
    const int* __restrict__ jbuf, const float* __restrict__ bw,
    const float* __restrict__ sw, float* __restrict__ out)
{
    int tid = threadIdx.x;
    int bl = tid >> 6;
    int ig = tid & 63;
    int b = blockIdx.x * 4 + bl;

    float acc = 0.f;
    for (int ii = ig; ii < 256; ii += 64) {
        float s = sbuf[ii * BATCH + b];
        float4 v = vbuf[ii * BATCH + b];
        int j = jbuf[ii * BATCH + b];
        const float* p = sw + (size_t)ii * NB + j;
        acc += s * bw[ii] + v.x * p[0] + v.y * p[1] + v.z * p[2] + v.w * p[3];
    }
#pragma unroll
    for (int dlt = 32; dlt >= 1; dlt >>= 1) acc += __shfl_down(acc, dlt, 64);
    if (ig == 0) out[b] = acc;
}

extern "C" void kernel_launch(void* const* d_in, const int* in_sizes, int n_in,
                              void* d_out, int out_size, void* d_ws, size_t ws_size,
                              hipStream_t stream)
{
    const float* x   = (const float*)d_in[0];
    const float* bw0 = (const float*)d_in[1];
    const float* sw0 = (const float*)d_in[2];
    const float* wb0 = (const float*)d_in[3];
    const float* ws0 = (const float*)d_in[4];
    const float* bw1 = (const float*)d_in[5];
    const float* sw1 = (const float*)d_in[6];
    const float* wb1 = (const float*)d_in[7];
    const float* ws1 = (const float*)d_in[8];
    const float* bw2 = (const float*)d_in[9];
    const float* sw2 = (const float*)d_in[10];
    const float* wb2 = (const float*)d_in[11];
    const float* ws2 = (const float*)d_in[12];
    const float* bw3 = (const float*)d_in[13];
    const float* sw3 = (const float*)d_in[14];
    const float* wb3 = (const float*)d_in[15];
    const float* ws3 = (const float*)d_in[16];

    char* ws = (char*)d_ws;
    float4* vbuf = (float4*)(ws);                        // 8 MB
    float*  sbuf = (float*)(ws + 8  * 1024 * 1024);      // 2 MB
    int*    jbuf = (int*)  (ws + 10 * 1024 * 1024);      // 2 MB
    float*  hA   = (float*)(ws + 12 * 1024 * 1024);      // 2 MB
    float*  hB   = (float*)(ws + 14 * 1024 * 1024);      // 2 MB

    float* out = (float*)d_out;

    dim3 ablk(128, 8);
    dim3 agrd(32, 16);   // 32 o-tiles x 16 b-tiles of 128

    // Layer 0: 64 -> 256, no residual
    basis_kernel<<<(BATCH * 64 + 255) / 256, 256, 0, stream>>>(x, 64, wb0, ws0, sbuf, vbuf, jbuf);
    accum_kernel<64, 8, false, 8, 128><<<agrd, ablk, 0, stream>>>(sbuf, vbuf, jbuf, bw0, sw0, nullptr, hA, 256);

    // Layer 1: 256 -> 256, residual
    basis_kernel<<<(BATCH * 256 + 255) / 256, 256, 0, stream>>>(hA, 256, wb1, ws1, sbuf, vbuf, jbuf);
    accum_kernel<256, 8, true, 8, 128><<<agrd, ablk, 0, stream>>>(sbuf, vbuf, jbuf, bw1, sw1, hA, hB, 256);

    // Layer 2: 256 -> 256, residual
    basis_kernel<<<(BATCH * 256 + 255) / 256, 256, 0, stream>>>(hB, 256, wb2, ws2, sbuf, vbuf, jbuf);
    accum_kernel<256, 8, true, 8, 128><<<agrd, ablk, 0, stream>>>(sbuf, vbuf, jbuf, bw2, sw2, hB, hA, 256);

    // Layer 3: 256 -> 1, no residual
    basis_kernel<<<(BATCH * 256 + 255) / 256, 256, 0, stream>>>(hA, 256, wb3, ws3, sbuf, vbuf, jbuf);
    out_kernel<<<BATCH / 4, 256, 0, stream>>>(sbuf, vbuf, jbuf, bw3, sw3, out);
}

// Round 4
// 295.222 us; speedup vs baseline: 1.5946x; 1.0159x over previous
//
#include <hip/hip_runtime.h>

#define BATCH 2048
#define NB 254

typedef float f4u __attribute__((ext_vector_type(4), aligned(4)));

__device__ __forceinline__ float selw(int pd, float w0, float w1, float w2, float w3) {
    return (pd == 0) ? w0 : (pd == 1) ? w1 : (pd == 2) ? w2 : (pd == 3) ? w3 : 0.f;
}

// Per (b,i): silu(x)*wb, 4 spline tap weights *ws (shifted into clamped window), window start j.
// TR: input activation layout. false: act[b][IN] (layer-0 x). true: act[i][BATCH] (transposed hidden).
template<bool TR>
__global__ __launch_bounds__(256) void basis_kernel(
    const float* __restrict__ act, int IN,
    const float* __restrict__ wbp, const float* __restrict__ wsp,
    float2* __restrict__ sjbuf, float4* __restrict__ vbuf)
{
    int idx = blockIdx.x * 256 + threadIdx.x;
    int total = BATCH * IN;
    if (idx >= total) return;
    int i = idx / BATCH;
    int b = idx - i * BATCH;

    float x = TR ? act[idx] : act[(size_t)b * IN + i];
    float wb = wbp[0], wsc = wsp[0];

    float sil = x / (1.f + __expf(-x));

    const float LO = -0.05f;
    const float INVH = 228.18181818181818f;  // 251/1.1
    float uf = (x - LO) * INVH;
    float fm = floorf(uf);
    float t = uf - fm;
    int M = (int)fm + 3;     // grid interval index: x in [GRID[M], GRID[M+1])

    bool valid = (M >= 0) && (M <= 256);
    float wsv = valid ? wsc : 0.f;

    float omt = 1.f - t;
    float t2 = t * t, t3 = t2 * t;
    const float S = 1.f / 6.f;
    float w0 = omt * omt * omt * S * wsv;
    float w1 = (3.f * t3 - 6.f * t2 + 4.f) * S * wsv;
    float w2 = (-3.f * t3 + 3.f * t2 + 3.f * t + 1.f) * S * wsv;
    float w3 = t3 * S * wsv;

    int js = M - 3;
    js = js < 0 ? 0 : js;
    js = js > (NB - 4) ? (NB - 4) : js;
    if (!valid) js = 0;
    int d = js - (M - 3);    // shift of taps inside the clamped window, in [-3,3]

    float vp0 = selw(0 + d, w0, w1, w2, w3);
    float vp1 = selw(1 + d, w0, w1, w2, w3);
    float vp2 = selw(2 + d, w0, w1, w2, w3);
    float vp3 = selw(3 + d, w0, w1, w2, w3);

    sjbuf[idx] = make_float2(sil * wb, __int_as_float(js));
    vbuf[idx] = make_float4(vp0, vp1, vp2, vp3);
}

// out[o][b] = sum_i ( s[b,i]*bw[o,i] + dot(v4[b,i], sw[o,i,j..j+3]) ) (+resid[o][b])
// Block: BT b-lanes (x) * IG i-groups (y). Wave == one i-group slice (BT=64).
// Output and residual are in TRANSPOSED [o][BATCH] layout.
template<int IN, int OT, bool RES, int IG, int BT>
__global__ __launch_bounds__(BT * IG) void accum_f32(
    const float2* __restrict__ sjbuf, const float4* __restrict__ vbuf,
    const float* __restrict__ bw, const float* __restrict__ sw,
    const float* __restrict__ resid, float* __restrict__ out)
{
    int bx = threadIdx.x;              // b lane within tile
    int g  = threadIdx.y;              // i-group (wave-uniform when BT==64)
    int b  = blockIdx.y * BT + bx;
    int o0 = blockIdx.x * OT;

    float acc[OT];
#pragma unroll
    for (int k = 0; k < OT; k++) acc[k] = 0.f;

    const size_t ostride = (size_t)IN * NB;
    const int CH = IN / IG;
    const int i0 = g * CH;

    for (int ii = 0; ii < CH; ii++) {
        int i = i0 + ii;
        float2 sj = sjbuf[i * BATCH + b];
        float4 v = vbuf[i * BATCH + b];
        int j = __float_as_int(sj.y);
        float s = sj.x;
        const float* p = sw + (size_t)(o0 * IN + i) * NB + j;
        const float* bq = bw + (size_t)o0 * IN + i;

        // stage all gathers first: 8 independent dwordx4 in flight per iter
        f4u w[OT];
#pragma unroll
        for (int oo = 0; oo < OT; oo++)
            w[oo] = *(const f4u*)(p + (size_t)oo * ostride);

#pragma unroll
        for (int oo = 0; oo < OT; oo++) {
            float bwv = bq[oo * IN];
            acc[oo] += s * bwv + v.x * w[oo][0] + v.y * w[oo][1] + v.z * w[oo][2] + v.w * w[oo][3];
        }
    }

    // LDS reduce across i-groups. Layout [oo][g-1][bx]: lane-stride 1, conflict-free.
    __shared__ float lds[OT * (IG - 1) * BT];
    if (g > 0) {
#pragma unroll
        for (int oo = 0; oo < OT; oo++)
            lds[(oo * (IG - 1) + (g - 1)) * BT + bx] = acc[oo];
    }
    __syncthreads();
    if (g == 0) {
#pragma unroll
        for (int oo = 0; oo < OT; oo++) {
            float a = acc[oo];
            for (int gg = 1; gg < IG; gg++)
                a += lds[(oo * (IG - 1) + (gg - 1)) * BT + bx];
            size_t oidx = (size_t)(o0 + oo) * BATCH + b;
            float r = RES ? resid[oidx] : 0.f;
            out[oidx] = a + r;
        }
    }
}

// Final layer: out=1, f32 weights. 64 lanes per batch row, shuffle-reduce.
__global__ __launch_bounds__(256) void out_kernel(
    const float2* __restrict__ sjbuf, const float4* __restrict__ vbuf,
    const float* __restrict__ bw, const float* __restrict__ sw,
    float* __restrict__ out)
{
    int tid = threadIdx.x;
    int bl = tid >> 6;
    int ig = tid & 63;
    int b = blockIdx.x * 4 + bl;

    float acc = 0.f;
    for (int ii = ig; ii < 256; ii += 64) {
        float2 sj = sjbuf[ii * BATCH + b];
        float4 v = vbuf[ii * BATCH + b];
        int j = __float_as_int(sj.y);
        const float* p = sw + (size_t)ii * NB + j;
        acc += sj.x * bw[ii] + v.x * p[0] + v.y * p[1] + v.z * p[2] + v.w * p[3];
    }
#pragma unroll
    for (int dlt = 32; dlt >= 1; dlt >>= 1) acc += __shfl_down(acc, dlt, 64);
    if (ig == 0) out[b] = acc;
}

extern "C" void kernel_launch(void* const* d_in, const int* in_sizes, int n_in,
                              void* d_out, int out_size, void* d_ws, size_t ws_size,
                              hipStream_t stream)
{
    const float* x   = (const float*)d_in[0];
    const float* bw0 = (const float*)d_in[1];
    const float* sw0 = (const float*)d_in[2];
    const float* wb0 = (const float*)d_in[3];
    const float* ws0 = (const float*)d_in[4];
    const float* bw1 = (const float*)d_in[5];
    const float* sw1 = (const float*)d_in[6];
    const float* wb1 = (const float*)d_in[7];
    const float* ws1 = (const float*)d_in[8];
    const float* bw2 = (const float*)d_in[9];
    const float* sw2 = (const float*)d_in[10];
    const float* wb2 = (const float*)d_in[11];
    const float* ws2 = (const float*)d_in[12];
    const float* bw3 = (const float*)d_in[13];
    const float* sw3 = (const float*)d_in[14];
    const float* wb3 = (const float*)d_in[15];
    const float* ws3 = (const float*)d_in[16];

    char* ws = (char*)d_ws;
    float4* vbuf  = (float4*)(ws);                        // 8 MB
    float2* sjbuf = (float2*)(ws + 8  * 1024 * 1024);     // 4 MB
    float*  hA    = (float*)(ws + 12 * 1024 * 1024);      // 2 MB  ([o][b] layout)
    float*  hB    = (float*)(ws + 14 * 1024 * 1024);      // 2 MB  ([o][b] layout)

    float* out = (float*)d_out;

    dim3 ablk(64, 8);     // BT=64 (one wave per i-group), IG=8 -> 512 threads
    dim3 agrd(32, 32);    // 32 o-tiles x 32 b-tiles of 64 -> 1024 blocks (4/CU)

    // Layer 0: 64 -> 256 (x is [b][64])
    basis_kernel<false><<<(BATCH * 64 + 255) / 256, 256, 0, stream>>>(x, 64, wb0, ws0, sjbuf, vbuf);
    accum_f32<64, 8, false, 8, 64><<<agrd, ablk, 0, stream>>>(sjbuf, vbuf, bw0, sw0, nullptr, hA);

    // Layer 1: 256 -> 256, residual (hA is [o][b] == [i][b] for next layer)
    basis_kernel<true><<<(BATCH * 256 + 255) / 256, 256, 0, stream>>>(hA, 256, wb1, ws1, sjbuf, vbuf);
    accum_f32<256, 8, true, 8, 64><<<agrd, ablk, 0, stream>>>(sjbuf, vbuf, bw1, sw1, hA, hB);

    // Layer 2: 256 -> 256, residual
    basis_kernel<true><<<(BATCH * 256 + 255) / 256, 256, 0, stream>>>(hB, 256, wb2, ws2, sjbuf, vbuf);
    accum_f32<256, 8, true, 8, 64><<<agrd, ablk, 0, stream>>>(sjbuf, vbuf, bw2, sw2, hB, hA);

    // Layer 3: 256 -> 1
    basis_kernel<true><<<(BATCH * 256 + 255) / 256, 256, 0, stream>>>(hA, 256, wb3, ws3, sjbuf, vbuf);
    out_kernel<<<BATCH / 4, 256, 0, stream>>>(sjbuf, vbuf, bw3, sw3, out);
}